// Round 19
// baseline (221.067 us; speedup 1.0000x reference)
//
#include <hip/hip_runtime.h>
#include <hip/hip_bf16.h>
#include <math.h>

#define D 64
#define NEG_GAT 0.2f
#define NEG_OUT 0.01f
#define CHUNK 256
#define MAXD 256   // LDS edge-cache capacity per node in k_agg; fallback below
#define BSH 8      // bucket = dst >> 8 (256-node windows)
#define NBMAX 512
#define PART_K 16  // edges per thread in k_part (4096 per block; grid stays > #CU)
#define NODE_BLOCKS 2048   // k_node grid (grid-stride; W-in-reg amortization)

typedef __hip_bfloat16 bf16;

// exact bf16->f32 from a packed u32 (low half = even element, high = odd)
__device__ __forceinline__ float bf_lo(unsigned u) { return __uint_as_float(u << 16); }
__device__ __forceinline__ float bf_hi(unsigned u) { return __uint_as_float(u & 0xffff0000u); }

// ================= fallback path (NB > NBMAX): r10-proven =================
__global__ void k_init(int* __restrict__ rp, int N) {
    int n = blockIdx.x * blockDim.x + threadIdx.x;
    if (n < N) rp[n] = 1;   // self-loop
}

__global__ void k_count(const int* __restrict__ dstI, int* __restrict__ rp, int E) {
    int i = blockIdx.x * blockDim.x + threadIdx.x;
    if (i < E) atomicAdd(&rp[dstI[i]], 1);
}

__global__ void k_scan1(const int* __restrict__ rp, int* __restrict__ partial, int N) {
    __shared__ int sm[CHUNK];
    int n = blockIdx.x * CHUNK + threadIdx.x;
    sm[threadIdx.x] = (n < N) ? rp[n] : 0;
    __syncthreads();
    for (int off = CHUNK / 2; off > 0; off >>= 1) {
        if (threadIdx.x < off) sm[threadIdx.x] += sm[threadIdx.x + off];
        __syncthreads();
    }
    if (threadIdx.x == 0) partial[blockIdx.x] = sm[0];
}

__global__ void k_scan2(int* __restrict__ partial, int NC) {
    __shared__ int sm[512];
    int t = threadIdx.x;
    int v = (t < NC) ? partial[t] : 0;
    sm[t] = v;
    __syncthreads();
    for (int off = 1; off < 512; off <<= 1) {
        int xv = (t >= off) ? sm[t - off] : 0;
        __syncthreads();
        sm[t] += xv;
        __syncthreads();
    }
    if (t < NC) partial[t] = sm[t] - v;   // exclusive
}

__global__ void k_scan3(int* __restrict__ rp, const int* __restrict__ partial, int N) {
    __shared__ int sm[CHUNK];
    int b = blockIdx.x, t = threadIdx.x;
    int n = b * CHUNK + t;
    int v = (n < N) ? rp[n] : 0;
    sm[t] = v;
    __syncthreads();
    for (int off = 1; off < CHUNK; off <<= 1) {
        int xv = (t >= off) ? sm[t - off] : 0;
        __syncthreads();
        sm[t] += xv;
        __syncthreads();
    }
    if (n < N) rp[n] = partial[b] + sm[t] - v;   // exclusive start
}

__global__ void k_place(const int* __restrict__ srcI, const int* __restrict__ dstI,
                        int* __restrict__ rp, int* __restrict__ perm, int E, int N) {
    int i = blockIdx.x * blockDim.x + threadIdx.x;
    if (i >= E + N) return;
    int dn, sn;
    if (i < E) { dn = dstI[i]; sn = srcI[i]; }
    else       { dn = i - E;   sn = dn; }
    int pos = atomicAdd(&rp[dn], 1);
    perm[pos] = sn;
}

// ================= bucketed path =================
__global__ void k_bzero(int* __restrict__ bh, int NB1) {
    int t = blockIdx.x * blockDim.x + threadIdx.x;
    if (t < NB1) bh[t] = 0;
}

__global__ void k_bscan(int* __restrict__ bh, int* __restrict__ bcur, int NB) {
    __shared__ int sm[NBMAX];
    int t = threadIdx.x;                 // blockDim == NBMAX
    int v = (t < NB) ? bh[t] : 0;
    sm[t] = v;
    __syncthreads();
    for (int off = 1; off < NBMAX; off <<= 1) {
        int xv = (t >= off) ? sm[t - off] : 0;
        __syncthreads();
        sm[t] += xv;
        __syncthreads();
    }
    if (t < NB) { int st = sm[t] - v; bh[t] = st; bcur[t] = st; }
}

// phase 1: bucket-partition with per-block LDS rank aggregation
__global__ void k_part(const int* __restrict__ srcI, const int* __restrict__ dstI,
                       int* __restrict__ bcur, unsigned* __restrict__ staging,
                       int E, int N) {
    __shared__ int lh[NBMAX];   // per-block bucket counts -> ranks
    __shared__ int gb[NBMAX];   // per-block global base per bucket
    const int EN = E + N;
    const int tid = threadIdx.x;
    const long long base = (long long)blockIdx.x * (256 * PART_K);

    for (int t = tid; t < NBMAX; t += 256) lh[t] = 0;
    __syncthreads();

    int bb[PART_K], rr[PART_K];
#pragma unroll
    for (int k = 0; k < PART_K; ++k) {
        long long i = base + (long long)k * 256 + tid;
        bb[k] = -1; rr[k] = 0;
        if (i < EN) {
            int dn = (i < E) ? dstI[i] : (int)(i - E);
            bb[k] = dn >> BSH;
            rr[k] = atomicAdd(&lh[bb[k]], 1);
        }
    }
    __syncthreads();
    for (int t = tid; t < NBMAX; t += 256) {
        int c = lh[t];
        gb[t] = c ? atomicAdd(&bcur[t], c) : 0;
    }
    __syncthreads();
#pragma unroll
    for (int k = 0; k < PART_K; ++k) {
        if (bb[k] >= 0) {
            long long i = base + (long long)k * 256 + tid;
            int dn, sn;
            if (i < E) { dn = dstI[i]; sn = srcI[i]; }
            else       { dn = (int)(i - E); sn = dn; }
            staging[(long long)gb[bb[k]] + rr[k]] =
                ((unsigned)sn << BSH) | (unsigned)(dn & ((1 << BSH) - 1));
        }
    }
}

// phase 2 (fused): per-bucket degree count + local scan -> rp (coalesced) + scatter
__global__ void k_place3(const unsigned* __restrict__ staging,
                         const int* __restrict__ bstart, const int* __restrict__ bend,
                         int* __restrict__ rp, int* __restrict__ perm, int N) {
    __shared__ int cnt[256];
    __shared__ int scan[256];
    const int b = blockIdx.x;
    const int t = threadIdx.x;          // blockDim == 256
    const int nbase = b << BSH;
    const int s = bstart[b], e = bend[b];

    cnt[t] = 0;
    __syncthreads();
    for (int j = s + t; j < e; j += 256)
        atomicAdd(&cnt[staging[j] & ((1 << BSH) - 1)], 1);
    __syncthreads();
    int v = cnt[t];
    scan[t] = v;
    __syncthreads();
    for (int off = 1; off < 256; off <<= 1) {
        int y = (t >= off) ? scan[t - off] : 0;
        __syncthreads();
        scan[t] += y;
        __syncthreads();
    }
    const int incl = scan[t];
    const int excl = incl - v;
    const int n = nbase + t;
    if (n < N) rp[n] = s + incl;         // global row END, coalesced
    __syncthreads();
    scan[t] = excl;                      // reuse as cursor
    __syncthreads();
    for (int j = s + t; j < e; j += 256) {
        unsigned pk = staging[j];
        int loc = pk & ((1 << BSH) - 1);
        int pos = s + atomicAdd(&scan[loc], 1);
        perm[pos] = (int)(pk >> BSH);
    }
}

// ---- node projection h = emb[x] @ W (W in registers, 4-node ILP), logits,
//      fused bucket-histogram tail (overlaps bhist's stream read with the
//      latency-bound node phase) ----
__global__ void __launch_bounds__(256)
k_node(const int* __restrict__ x,
       const float* __restrict__ emb,
       const float* __restrict__ W,
       const float* __restrict__ att_src,
       const float* __restrict__ att_dst,
       bf16* __restrict__ hb,
       float* __restrict__ a_src, float* __restrict__ a_dst,
       const int* __restrict__ dstI, int* __restrict__ bh, int E,
       int N)
{
    __shared__ float Wl[D * D];
    __shared__ int lh[NBMAX];
    for (int i = threadIdx.x; i < D * D; i += blockDim.x) Wl[i] = W[i];
    __syncthreads();

    const int lane = threadIdx.x & 63;
    const int wave = threadIdx.x >> 6;

    float wreg[D];
#pragma unroll
    for (int d = 0; d < D; ++d) wreg[d] = Wl[d * D + lane];

    const float asl = att_src[lane];
    const float adl = att_dst[lane];
    const int stride = gridDim.x * 4;

    int n = blockIdx.x * 4 + wave;
    // 4 independent scalar-load + FMA chains in flight per wave
    for (; n + 3 * stride < N; n += 4 * stride) {
        const int na = n, nb2 = n + stride, nc = n + 2 * stride, nd = n + 3 * stride;
        const int xa = __builtin_amdgcn_readfirstlane(x[na]);
        const int xb = __builtin_amdgcn_readfirstlane(x[nb2]);
        const int xc = __builtin_amdgcn_readfirstlane(x[nc]);
        const int xd = __builtin_amdgcn_readfirstlane(x[nd]);
        const float* ea = emb + (long long)xa * D;
        const float* eb = emb + (long long)xb * D;
        const float* ec = emb + (long long)xc * D;
        const float* ed = emb + (long long)xd * D;

        float h1 = 0.0f, h2 = 0.0f, h3 = 0.0f, h4 = 0.0f;
#pragma unroll
        for (int d = 0; d < D; ++d) {
            h1 = fmaf(ea[d], wreg[d], h1);
            h2 = fmaf(eb[d], wreg[d], h2);
            h3 = fmaf(ec[d], wreg[d], h3);
            h4 = fmaf(ed[d], wreg[d], h4);
        }
        hb[(long long)na  * D + lane] = __float2bfloat16(h1);
        hb[(long long)nb2 * D + lane] = __float2bfloat16(h2);
        hb[(long long)nc  * D + lane] = __float2bfloat16(h3);
        hb[(long long)nd  * D + lane] = __float2bfloat16(h4);

        float vs1 = h1 * asl, vd1 = h1 * adl;
        float vs2 = h2 * asl, vd2 = h2 * adl;
        float vs3 = h3 * asl, vd3 = h3 * adl;
        float vs4 = h4 * asl, vd4 = h4 * adl;
#pragma unroll
        for (int o = 32; o >= 1; o >>= 1) {
            vs1 += __shfl_xor(vs1, o);  vd1 += __shfl_xor(vd1, o);
            vs2 += __shfl_xor(vs2, o);  vd2 += __shfl_xor(vd2, o);
            vs3 += __shfl_xor(vs3, o);  vd3 += __shfl_xor(vd3, o);
            vs4 += __shfl_xor(vs4, o);  vd4 += __shfl_xor(vd4, o);
        }
        if (lane == 0) {
            a_src[na]  = vs1; a_dst[na]  = vd1;
            a_src[nb2] = vs2; a_dst[nb2] = vd2;
            a_src[nc]  = vs3; a_dst[nc]  = vd3;
            a_src[nd]  = vs4; a_dst[nd]  = vd4;
        }
    }
    // tail singles
    for (; n < N; n += stride) {
        const int xn = __builtin_amdgcn_readfirstlane(x[n]);
        const float* er = emb + (long long)xn * D;
        float hc = 0.0f;
#pragma unroll
        for (int d = 0; d < D; ++d)
            hc = fmaf(er[d], wreg[d], hc);
        hb[(long long)n * D + lane] = __float2bfloat16(hc);
        float vs = hc * asl, vd = hc * adl;
#pragma unroll
        for (int o = 32; o >= 1; o >>= 1) {
            vs += __shfl_xor(vs, o);
            vd += __shfl_xor(vd, o);
        }
        if (lane == 0) { a_src[n] = vs; a_dst[n] = vd; }
    }

    // ---- fused bucket histogram (bucketed path only) ----
    if (bh) {
        for (int t = threadIdx.x; t < NBMAX; t += 256) lh[t] = 0;
        __syncthreads();
        const long long EN = (long long)E + N;
        for (long long i = (long long)blockIdx.x * blockDim.x + threadIdx.x; i < EN;
             i += (long long)gridDim.x * blockDim.x) {
            int dn = (i < E) ? dstI[i] : (int)(i - E);
            atomicAdd(&lh[dn >> BSH], 1);
        }
        __syncthreads();
        for (int t = threadIdx.x; t < NBMAX; t += 256)
            if (lh[t]) atomicAdd(&bh[t], lh[t]);
    }
}

// ---- per-dst softmax + aggregation (1 wave / node, LDS edge cache, bf16 h) ----
__global__ void k_agg(const int* __restrict__ rp,   // rp[n] = end of row n
                      const int* __restrict__ perm, // src node per CSR slot
                      const float* __restrict__ a_src,
                      const float* __restrict__ a_dst,
                      const bf16* __restrict__ hb,
                      const float* __restrict__ bias,
                      float* __restrict__ out,
                      float2* __restrict__ adsc,      // ws: {a_dst[n], scale[n]}
                      int E, int N)
{
    __shared__ int   sn_s[4][MAXD];
    __shared__ float al_s[4][MAXD];

    const int lane = threadIdx.x & 63;
    const int w    = threadIdx.x >> 6;
    const int n = blockIdx.x * 4 + w;
    if (n >= N) return;

    const int base = (n == 0) ? 0 : rp[n - 1];
    const int deg  = rp[n] - base;
    const float adn = a_dst[n];

    if (deg <= MAXD) {
        float mx = -1e30f;
        for (int j = lane; j < deg; j += 64) {
            int sn = perm[base + j];
            sn_s[w][j] = sn;
            float lg = a_src[sn] + adn;
            lg = lg > 0.0f ? lg : NEG_GAT * lg;
            al_s[w][j] = lg;
            mx = fmaxf(mx, lg);
        }
#pragma unroll
        for (int o = 32; o >= 1; o >>= 1) mx = fmaxf(mx, __shfl_xor(mx, o));

        float se = 0.0f;
        for (int j = lane; j < deg; j += 64) {
            float ex = __expf(al_s[w][j] - mx);
            al_s[w][j] = ex;
            se += ex;
        }
#pragma unroll
        for (int o = 32; o >= 1; o >>= 1) se += __shfl_xor(se, o);
        const float inv = 1.0f / (se + 1e-16f);
        if (lane == 0) adsc[n] = make_float2(adn, inv * __expf(-mx));

        const int e = lane >> 3;
        const int c = lane & 7;
        float acc[8] = {0.f, 0.f, 0.f, 0.f, 0.f, 0.f, 0.f, 0.f};
#pragma unroll 2
        for (int j = e; j < deg; j += 8) {
            const float al = al_s[w][j];
            const uint4 u =
                reinterpret_cast<const uint4*>(hb + (long long)sn_s[w][j] * D)[c];
            acc[0] = fmaf(al, bf_lo(u.x), acc[0]);
            acc[1] = fmaf(al, bf_hi(u.x), acc[1]);
            acc[2] = fmaf(al, bf_lo(u.y), acc[2]);
            acc[3] = fmaf(al, bf_hi(u.y), acc[3]);
            acc[4] = fmaf(al, bf_lo(u.z), acc[4]);
            acc[5] = fmaf(al, bf_hi(u.z), acc[5]);
            acc[6] = fmaf(al, bf_lo(u.w), acc[6]);
            acc[7] = fmaf(al, bf_hi(u.w), acc[7]);
        }
#pragma unroll
        for (int o = 8; o <= 32; o <<= 1) {
#pragma unroll
            for (int k = 0; k < 8; ++k) acc[k] += __shfl_xor(acc[k], o);
        }

        if (lane < 8) {
            const float4 b0 = reinterpret_cast<const float4*>(bias)[2 * c];
            const float4 b1 = reinterpret_cast<const float4*>(bias)[2 * c + 1];
            float4 v0, v1;
            v0.x = acc[0] * inv + b0.x;
            v0.y = acc[1] * inv + b0.y;
            v0.z = acc[2] * inv + b0.z;
            v0.w = acc[3] * inv + b0.w;
            v1.x = acc[4] * inv + b1.x;
            v1.y = acc[5] * inv + b1.y;
            v1.z = acc[6] * inv + b1.z;
            v1.w = acc[7] * inv + b1.w;
            v0.x = v0.x > 0.0f ? v0.x : NEG_OUT * v0.x;
            v0.y = v0.y > 0.0f ? v0.y : NEG_OUT * v0.y;
            v0.z = v0.z > 0.0f ? v0.z : NEG_OUT * v0.z;
            v0.w = v0.w > 0.0f ? v0.w : NEG_OUT * v0.w;
            v1.x = v1.x > 0.0f ? v1.x : NEG_OUT * v1.x;
            v1.y = v1.y > 0.0f ? v1.y : NEG_OUT * v1.y;
            v1.z = v1.z > 0.0f ? v1.z : NEG_OUT * v1.z;
            v1.w = v1.w > 0.0f ? v1.w : NEG_OUT * v1.w;
            float4* orow = reinterpret_cast<float4*>(out + (long long)n * D);
            orow[2 * c]     = v0;
            orow[2 * c + 1] = v1;
        }
    } else {
        float mx = -1e30f;
        for (int j = lane; j < deg; j += 64) {
            int sn = perm[base + j];
            float lg = a_src[sn] + adn;
            lg = lg > 0.0f ? lg : NEG_GAT * lg;
            mx = fmaxf(mx, lg);
        }
#pragma unroll
        for (int o = 32; o >= 1; o >>= 1) mx = fmaxf(mx, __shfl_xor(mx, o));

        float se = 0.0f;
        for (int j = lane; j < deg; j += 64) {
            int sn = perm[base + j];
            float lg = a_src[sn] + adn;
            lg = lg > 0.0f ? lg : NEG_GAT * lg;
            se += __expf(lg - mx);
        }
#pragma unroll
        for (int o = 32; o >= 1; o >>= 1) se += __shfl_xor(se, o);
        const float inv = 1.0f / (se + 1e-16f);
        if (lane == 0) adsc[n] = make_float2(adn, inv * __expf(-mx));

        float acc = 0.0f;
        for (int j = 0; j < deg; ++j) {
            int sn = perm[base + j];
            float lg = a_src[sn] + adn;
            lg = lg > 0.0f ? lg : NEG_GAT * lg;
            float al = __expf(lg - mx) * inv;
            acc = fmaf(al, __bfloat162float(hb[(long long)sn * D + lane]), acc);
        }
        float v = acc + bias[lane];
        v = v > 0.0f ? v : NEG_OUT * v;
        out[(long long)n * D + lane] = v;
    }
}

// ---- alpha for ALL E+N entries: 4/thread, packed {a_dst,scale} gather ----
__global__ void k_alpha4(const int* __restrict__ srcI, const int* __restrict__ dstI,
                         const float* __restrict__ a_src,
                         const float2* __restrict__ adsc,
                         float* __restrict__ alpha_out, int E, int N)
{
    const int i4 = (blockIdx.x * blockDim.x + threadIdx.x) * 4;
    const int EN = E + N;
    if (i4 >= EN) return;
    if (i4 + 3 < E) {
        const int4 s4 = *reinterpret_cast<const int4*>(srcI + i4);
        const int4 d4 = *reinterpret_cast<const int4*>(dstI + i4);
        float4 r;
        {
            const float2 ad = adsc[d4.x];
            float lg = a_src[s4.x] + ad.x;
            lg = lg > 0.0f ? lg : NEG_GAT * lg;
            r.x = __expf(lg) * ad.y;
        }
        {
            const float2 ad = adsc[d4.y];
            float lg = a_src[s4.y] + ad.x;
            lg = lg > 0.0f ? lg : NEG_GAT * lg;
            r.y = __expf(lg) * ad.y;
        }
        {
            const float2 ad = adsc[d4.z];
            float lg = a_src[s4.z] + ad.x;
            lg = lg > 0.0f ? lg : NEG_GAT * lg;
            r.z = __expf(lg) * ad.y;
        }
        {
            const float2 ad = adsc[d4.w];
            float lg = a_src[s4.w] + ad.x;
            lg = lg > 0.0f ? lg : NEG_GAT * lg;
            r.w = __expf(lg) * ad.y;
        }
        *reinterpret_cast<float4*>(alpha_out + i4) = r;
    } else {
#pragma unroll
        for (int k = 0; k < 4; ++k) {
            int i = i4 + k;
            if (i >= EN) break;
            int sn, dn;
            if (i < E) { sn = srcI[i]; dn = dstI[i]; }
            else       { sn = dn = i - E; }
            const float2 ad = adsc[dn];
            float lg = a_src[sn] + ad.x;
            lg = lg > 0.0f ? lg : NEG_GAT * lg;
            alpha_out[i] = __expf(lg) * ad.y;
        }
    }
}

// scalar fallback (any E)
__global__ void k_alpha(const int* __restrict__ srcI, const int* __restrict__ dstI,
                        const float* __restrict__ a_src,
                        const float2* __restrict__ adsc,
                        float* __restrict__ alpha_out, int E, int N)
{
    int i = blockIdx.x * blockDim.x + threadIdx.x;
    if (i >= E + N) return;
    int sn, dn;
    if (i < E) { sn = srcI[i]; dn = dstI[i]; }
    else       { sn = dn = i - E; }
    const float2 ad = adsc[dn];
    float lg = a_src[sn] + ad.x;
    lg = lg > 0.0f ? lg : NEG_GAT * lg;
    alpha_out[i] = __expf(lg) * ad.y;
}

extern "C" void kernel_launch(void* const* d_in, const int* in_sizes, int n_in,
                              void* d_out, int out_size, void* d_ws, size_t ws_size,
                              hipStream_t stream)
{
    const int* x          = (const int*)d_in[0];
    const int* ei         = (const int*)d_in[1];
    const float* emb      = (const float*)d_in[2];
    const float* W        = (const float*)d_in[3];
    const float* att_src  = (const float*)d_in[4];
    const float* att_dst  = (const float*)d_in[5];
    const float* bias     = (const float*)d_in[6];

    const int N = in_sizes[0];
    const int E = in_sizes[1] / 2;
    const int* srcI = ei;       // edge_index[0]
    const int* dstI = ei + E;   // edge_index[1]
    const int NC = (N + CHUNK - 1) / CHUNK;
    const int NB = (N + (1 << BSH) - 1) >> BSH;
    const int EN = E + N;

    char* p = (char*)d_ws;
    size_t off = 0;
    auto take = [&](size_t bytes) {
        char* q = p + off;
        off += (bytes + 15) & ~size_t(15);
        return q;
    };
    int* partial      = (int*)take((size_t)NC * 4);
    int* rp           = (int*)take((size_t)N * 4);
    float* a_src_b    = (float*)take((size_t)N * 4);
    float* a_dst_b    = (float*)take((size_t)N * 4);
    float2* adsc      = (float2*)take((size_t)N * 8);
    int* perm         = (int*)take((size_t)EN * 4);
    int* bh           = (int*)take((size_t)(NBMAX + 1) * 4);
    int* bcur         = (int*)take((size_t)NBMAX * 4);
    unsigned* staging = (unsigned*)take((size_t)EN * 4);   // no aliasing (replay-safe, r13)
    bf16* hb          = (bf16*)take((size_t)N * D * 2);    // total ~28.4 MB (< proven 33.6)

    float* out       = (float*)d_out;
    float* alpha_out = out + (long long)N * D;

    const bool bucketed = (NB <= NBMAX) && (N < (1 << 23));
    const int node_grid = min(NODE_BLOCKS, (N + 3) / 4);

    if (bucketed) {
        k_bzero <<<(NBMAX + 256) / 256, 256, 0, stream>>>(bh, NBMAX + 1);
        k_node  <<<node_grid, 256, 0, stream>>>(x, emb, W, att_src, att_dst,
                                                hb, a_src_b, a_dst_b,
                                                dstI, bh, E, N);
        k_bscan <<<1, NBMAX, 0, stream>>>(bh, bcur, NB);
        k_part  <<<(EN + 256 * PART_K - 1) / (256 * PART_K), 256, 0, stream>>>(
                    srcI, dstI, bcur, staging, E, N);
        k_place3<<<NB, 256, 0, stream>>>(staging, bh, bcur, rp, perm, N);
    } else {
        k_node  <<<node_grid, 256, 0, stream>>>(x, emb, W, att_src, att_dst,
                                                hb, a_src_b, a_dst_b,
                                                dstI, (int*)nullptr, E, N);
        k_init  <<<(N + 255) / 256, 256, 0, stream>>>(rp, N);
        k_count <<<(E + 255) / 256, 256, 0, stream>>>(dstI, rp, E);
        k_scan1 <<<NC, CHUNK, 0, stream>>>(rp, partial, N);
        k_scan2 <<<1, 512, 0, stream>>>(partial, NC);
        k_scan3 <<<NC, CHUNK, 0, stream>>>(rp, partial, N);
        k_place <<<(EN + 255) / 256, 256, 0, stream>>>(srcI, dstI, rp, perm, E, N);
    }
    k_agg  <<<(N + 3) / 4, 256, 0, stream>>>(rp, perm, a_src_b, a_dst_b,
                                             hb, bias, out, adsc, E, N);
    if ((E & 3) == 0) {
        k_alpha4<<<((EN + 3) / 4 + 255) / 256, 256, 0, stream>>>(
                    srcI, dstI, a_src_b, adsc, alpha_out, E, N);
    } else {
        k_alpha <<<(EN + 255) / 256, 256, 0, stream>>>(
                    srcI, dstI, a_src_b, adsc, alpha_out, E, N);
    }
}

// Round 20
// 193.189 us; speedup vs baseline: 1.1443x; 1.1443x over previous
//
#include <hip/hip_runtime.h>
#include <hip/hip_bf16.h>
#include <math.h>

#define D 64
#define NEG_GAT 0.2f
#define NEG_OUT 0.01f
#define CHUNK 256
#define MAXD 256   // LDS edge-cache capacity per node in k_agg; fallback below
#define BSH 8      // bucket = dst >> 8 (256-node windows)
#define NBMAX 512
#define PART_K 16  // edges per thread in k_part (4096 per block)
#define NODE_BLOCKS 2048   // k_node grid (grid-stride; W-in-reg amortization)

typedef __hip_bfloat16 bf16;

// exact bf16->f32 from a packed u32 (low half = even element, high = odd)
__device__ __forceinline__ float bf_lo(unsigned u) { return __uint_as_float(u << 16); }
__device__ __forceinline__ float bf_hi(unsigned u) { return __uint_as_float(u & 0xffff0000u); }

// ================= fallback path (NB > NBMAX): r10-proven =================
__global__ void k_init(int* __restrict__ rp, int N) {
    int n = blockIdx.x * blockDim.x + threadIdx.x;
    if (n < N) rp[n] = 1;   // self-loop
}

__global__ void k_count(const int* __restrict__ dstI, int* __restrict__ rp, int E) {
    int i = blockIdx.x * blockDim.x + threadIdx.x;
    if (i < E) atomicAdd(&rp[dstI[i]], 1);
}

__global__ void k_scan1(const int* __restrict__ rp, int* __restrict__ partial, int N) {
    __shared__ int sm[CHUNK];
    int n = blockIdx.x * CHUNK + threadIdx.x;
    sm[threadIdx.x] = (n < N) ? rp[n] : 0;
    __syncthreads();
    for (int off = CHUNK / 2; off > 0; off >>= 1) {
        if (threadIdx.x < off) sm[threadIdx.x] += sm[threadIdx.x + off];
        __syncthreads();
    }
    if (threadIdx.x == 0) partial[blockIdx.x] = sm[0];
}

__global__ void k_scan2(int* __restrict__ partial, int NC) {
    __shared__ int sm[512];
    int t = threadIdx.x;
    int v = (t < NC) ? partial[t] : 0;
    sm[t] = v;
    __syncthreads();
    for (int off = 1; off < 512; off <<= 1) {
        int xv = (t >= off) ? sm[t - off] : 0;
        __syncthreads();
        sm[t] += xv;
        __syncthreads();
    }
    if (t < NC) partial[t] = sm[t] - v;   // exclusive
}

__global__ void k_scan3(int* __restrict__ rp, const int* __restrict__ partial, int N) {
    __shared__ int sm[CHUNK];
    int b = blockIdx.x, t = threadIdx.x;
    int n = b * CHUNK + t;
    int v = (n < N) ? rp[n] : 0;
    sm[t] = v;
    __syncthreads();
    for (int off = 1; off < CHUNK; off <<= 1) {
        int xv = (t >= off) ? sm[t - off] : 0;
        __syncthreads();
        sm[t] += xv;
        __syncthreads();
    }
    if (n < N) rp[n] = partial[b] + sm[t] - v;   // exclusive start
}

__global__ void k_place(const int* __restrict__ srcI, const int* __restrict__ dstI,
                        int* __restrict__ rp, int* __restrict__ perm, int E, int N) {
    int i = blockIdx.x * blockDim.x + threadIdx.x;
    if (i >= E + N) return;
    int dn, sn;
    if (i < E) { dn = dstI[i]; sn = srcI[i]; }
    else       { dn = i - E;   sn = dn; }
    int pos = atomicAdd(&rp[dn], 1);
    perm[pos] = sn;
}

// ================= bucketed path =================
__global__ void k_bzero(int* __restrict__ bh, int NB1) {
    int t = blockIdx.x * blockDim.x + threadIdx.x;
    if (t < NB1) bh[t] = 0;
}

__global__ void k_bhist(const int* __restrict__ dstI, int* __restrict__ bh,
                        int E, int N) {
    __shared__ int lh[NBMAX];
    for (int t = threadIdx.x; t < NBMAX; t += blockDim.x) lh[t] = 0;
    __syncthreads();
    const int EN = E + N;
    for (int i = blockIdx.x * blockDim.x + threadIdx.x; i < EN;
         i += gridDim.x * blockDim.x) {
        int dn = (i < E) ? dstI[i] : (i - E);
        atomicAdd(&lh[dn >> BSH], 1);
    }
    __syncthreads();
    for (int t = threadIdx.x; t < NBMAX; t += blockDim.x)
        if (lh[t]) atomicAdd(&bh[t], lh[t]);
}

__global__ void k_bscan(int* __restrict__ bh, int* __restrict__ bcur, int NB) {
    __shared__ int sm[NBMAX];
    int t = threadIdx.x;                 // blockDim == NBMAX
    int v = (t < NB) ? bh[t] : 0;
    sm[t] = v;
    __syncthreads();
    for (int off = 1; off < NBMAX; off <<= 1) {
        int xv = (t >= off) ? sm[t - off] : 0;
        __syncthreads();
        sm[t] += xv;
        __syncthreads();
    }
    if (t < NB) { int st = sm[t] - v; bh[t] = st; bcur[t] = st; }
}

// phase 1: bucket-partition with per-block LDS rank aggregation
__global__ void k_part(const int* __restrict__ srcI, const int* __restrict__ dstI,
                       int* __restrict__ bcur, unsigned* __restrict__ staging,
                       int E, int N) {
    __shared__ int lh[NBMAX];   // per-block bucket counts -> ranks
    __shared__ int gb[NBMAX];   // per-block global base per bucket
    const int EN = E + N;
    const int tid = threadIdx.x;
    const long long base = (long long)blockIdx.x * (256 * PART_K);

    for (int t = tid; t < NBMAX; t += 256) lh[t] = 0;
    __syncthreads();

    int bb[PART_K], rr[PART_K];
#pragma unroll
    for (int k = 0; k < PART_K; ++k) {
        long long i = base + (long long)k * 256 + tid;
        bb[k] = -1; rr[k] = 0;
        if (i < EN) {
            int dn = (i < E) ? dstI[i] : (int)(i - E);
            bb[k] = dn >> BSH;
            rr[k] = atomicAdd(&lh[bb[k]], 1);
        }
    }
    __syncthreads();
    for (int t = tid; t < NBMAX; t += 256) {
        int c = lh[t];
        gb[t] = c ? atomicAdd(&bcur[t], c) : 0;
    }
    __syncthreads();
#pragma unroll
    for (int k = 0; k < PART_K; ++k) {
        if (bb[k] >= 0) {
            long long i = base + (long long)k * 256 + tid;
            int dn, sn;
            if (i < E) { dn = dstI[i]; sn = srcI[i]; }
            else       { dn = (int)(i - E); sn = dn; }
            staging[(long long)gb[bb[k]] + rr[k]] =
                ((unsigned)sn << BSH) | (unsigned)(dn & ((1 << BSH) - 1));
        }
    }
}

// phase 2 (fused): per-bucket degree count + local scan -> rp (coalesced) + scatter
__global__ void k_place3(const unsigned* __restrict__ staging,
                         const int* __restrict__ bstart, const int* __restrict__ bend,
                         int* __restrict__ rp, int* __restrict__ perm, int N) {
    __shared__ int cnt[256];
    __shared__ int scan[256];
    const int b = blockIdx.x;
    const int t = threadIdx.x;          // blockDim == 256
    const int nbase = b << BSH;
    const int s = bstart[b], e = bend[b];

    cnt[t] = 0;
    __syncthreads();
    for (int j = s + t; j < e; j += 256)
        atomicAdd(&cnt[staging[j] & ((1 << BSH) - 1)], 1);
    __syncthreads();
    int v = cnt[t];
    scan[t] = v;
    __syncthreads();
    for (int off = 1; off < 256; off <<= 1) {
        int y = (t >= off) ? scan[t - off] : 0;
        __syncthreads();
        scan[t] += y;
        __syncthreads();
    }
    const int incl = scan[t];
    const int excl = incl - v;
    const int n = nbase + t;
    if (n < N) rp[n] = s + incl;         // global row END, coalesced
    __syncthreads();
    scan[t] = excl;                      // reuse as cursor
    __syncthreads();
    for (int j = s + t; j < e; j += 256) {
        unsigned pk = staging[j];
        int loc = pk & ((1 << BSH) - 1);
        int pos = s + atomicAdd(&scan[loc], 1);
        perm[pos] = (int)(pk >> BSH);
    }
}

// ---- node projection h = emb[x] @ W (W in registers), attention logits ----
__global__ void __launch_bounds__(256)
k_node(const int* __restrict__ x,
       const float* __restrict__ emb,
       const float* __restrict__ W,
       const float* __restrict__ att_src,
       const float* __restrict__ att_dst,
       bf16* __restrict__ hb,
       float* __restrict__ a_src, float* __restrict__ a_dst,
       int N)
{
    __shared__ float Wl[D * D];
    for (int i = threadIdx.x; i < D * D; i += blockDim.x) Wl[i] = W[i];
    __syncthreads();

    const int lane = threadIdx.x & 63;
    const int wave = threadIdx.x >> 6;

    float wreg[D];
#pragma unroll
    for (int d = 0; d < D; ++d) wreg[d] = Wl[d * D + lane];

    const float asl = att_src[lane];
    const float adl = att_dst[lane];

    for (int n = blockIdx.x * 4 + wave; n < N; n += gridDim.x * 4) {
        const int xn = __builtin_amdgcn_readfirstlane(x[n]);
        const float* er = emb + (long long)xn * D;

        float hc = 0.0f;
#pragma unroll
        for (int d = 0; d < D; ++d)
            hc = fmaf(er[d], wreg[d], hc);

        hb[(long long)n * D + lane] = __float2bfloat16(hc);

        float vs = hc * asl;
        float vd = hc * adl;
#pragma unroll
        for (int o = 32; o >= 1; o >>= 1) {
            vs += __shfl_xor(vs, o);
            vd += __shfl_xor(vd, o);
        }
        if (lane == 0) { a_src[n] = vs; a_dst[n] = vd; }
    }
}

// ---- per-dst softmax + aggregation (1 wave / node, LDS edge cache, bf16 h) ----
__global__ void k_agg(const int* __restrict__ rp,   // rp[n] = end of row n
                      const int* __restrict__ perm, // src node per CSR slot
                      const float* __restrict__ a_src,
                      const float* __restrict__ a_dst,
                      const bf16* __restrict__ hb,
                      const float* __restrict__ bias,
                      float* __restrict__ out,
                      float* __restrict__ scale_ws,   // ws: per-node alpha scale
                      int E, int N)
{
    __shared__ int   sn_s[4][MAXD];
    __shared__ float al_s[4][MAXD];

    const int lane = threadIdx.x & 63;
    const int w    = threadIdx.x >> 6;
    const int n = blockIdx.x * 4 + w;
    if (n >= N) return;

    const int base = (n == 0) ? 0 : rp[n - 1];
    const int deg  = rp[n] - base;
    const float adn = a_dst[n];

    if (deg <= MAXD) {
        float mx = -1e30f;
        for (int j = lane; j < deg; j += 64) {
            int sn = perm[base + j];
            sn_s[w][j] = sn;
            float lg = a_src[sn] + adn;
            lg = lg > 0.0f ? lg : NEG_GAT * lg;
            al_s[w][j] = lg;
            mx = fmaxf(mx, lg);
        }
#pragma unroll
        for (int o = 32; o >= 1; o >>= 1) mx = fmaxf(mx, __shfl_xor(mx, o));

        float se = 0.0f;
        for (int j = lane; j < deg; j += 64) {
            float ex = __expf(al_s[w][j] - mx);
            al_s[w][j] = ex;
            se += ex;
        }
#pragma unroll
        for (int o = 32; o >= 1; o >>= 1) se += __shfl_xor(se, o);
        const float inv = 1.0f / (se + 1e-16f);
        if (lane == 0) scale_ws[n] = inv * __expf(-mx);

        const int e = lane >> 3;
        const int c = lane & 7;
        float acc[8] = {0.f, 0.f, 0.f, 0.f, 0.f, 0.f, 0.f, 0.f};
#pragma unroll 2
        for (int j = e; j < deg; j += 8) {
            const float al = al_s[w][j];
            const uint4 u =
                reinterpret_cast<const uint4*>(hb + (long long)sn_s[w][j] * D)[c];
            acc[0] = fmaf(al, bf_lo(u.x), acc[0]);
            acc[1] = fmaf(al, bf_hi(u.x), acc[1]);
            acc[2] = fmaf(al, bf_lo(u.y), acc[2]);
            acc[3] = fmaf(al, bf_hi(u.y), acc[3]);
            acc[4] = fmaf(al, bf_lo(u.z), acc[4]);
            acc[5] = fmaf(al, bf_hi(u.z), acc[5]);
            acc[6] = fmaf(al, bf_lo(u.w), acc[6]);
            acc[7] = fmaf(al, bf_hi(u.w), acc[7]);
        }
#pragma unroll
        for (int o = 8; o <= 32; o <<= 1) {
#pragma unroll
            for (int k = 0; k < 8; ++k) acc[k] += __shfl_xor(acc[k], o);
        }

        if (lane < 8) {   // lane == c; owns channels 8c..8c+7
            const float4 b0 = reinterpret_cast<const float4*>(bias)[2 * c];
            const float4 b1 = reinterpret_cast<const float4*>(bias)[2 * c + 1];
            float4 v0, v1;
            v0.x = acc[0] * inv + b0.x;
            v0.y = acc[1] * inv + b0.y;
            v0.z = acc[2] * inv + b0.z;
            v0.w = acc[3] * inv + b0.w;
            v1.x = acc[4] * inv + b1.x;
            v1.y = acc[5] * inv + b1.y;
            v1.z = acc[6] * inv + b1.z;
            v1.w = acc[7] * inv + b1.w;
            v0.x = v0.x > 0.0f ? v0.x : NEG_OUT * v0.x;
            v0.y = v0.y > 0.0f ? v0.y : NEG_OUT * v0.y;
            v0.z = v0.z > 0.0f ? v0.z : NEG_OUT * v0.z;
            v0.w = v0.w > 0.0f ? v0.w : NEG_OUT * v0.w;
            v1.x = v1.x > 0.0f ? v1.x : NEG_OUT * v1.x;
            v1.y = v1.y > 0.0f ? v1.y : NEG_OUT * v1.y;
            v1.z = v1.z > 0.0f ? v1.z : NEG_OUT * v1.z;
            v1.w = v1.w > 0.0f ? v1.w : NEG_OUT * v1.w;
            float4* orow = reinterpret_cast<float4*>(out + (long long)n * D);
            orow[2 * c]     = v0;
            orow[2 * c + 1] = v1;
        }
    } else {
        float mx = -1e30f;
        for (int j = lane; j < deg; j += 64) {
            int sn = perm[base + j];
            float lg = a_src[sn] + adn;
            lg = lg > 0.0f ? lg : NEG_GAT * lg;
            mx = fmaxf(mx, lg);
        }
#pragma unroll
        for (int o = 32; o >= 1; o >>= 1) mx = fmaxf(mx, __shfl_xor(mx, o));

        float se = 0.0f;
        for (int j = lane; j < deg; j += 64) {
            int sn = perm[base + j];
            float lg = a_src[sn] + adn;
            lg = lg > 0.0f ? lg : NEG_GAT * lg;
            se += __expf(lg - mx);
        }
#pragma unroll
        for (int o = 32; o >= 1; o >>= 1) se += __shfl_xor(se, o);
        const float inv = 1.0f / (se + 1e-16f);
        if (lane == 0) scale_ws[n] = inv * __expf(-mx);

        float acc = 0.0f;
        for (int j = 0; j < deg; ++j) {
            int sn = perm[base + j];
            float lg = a_src[sn] + adn;
            lg = lg > 0.0f ? lg : NEG_GAT * lg;
            float al = __expf(lg - mx) * inv;
            acc = fmaf(al, __bfloat162float(hb[(long long)sn * D + lane]), acc);
        }
        float v = acc + bias[lane];
        v = v > 0.0f ? v : NEG_OUT * v;
        out[(long long)n * D + lane] = v;
    }
}

// ---- alpha in edge order (coalesced writes) ----
__global__ void k_alphaE(const int* __restrict__ srcI, const int* __restrict__ dstI,
                         const float* __restrict__ a_src, const float* __restrict__ a_dst,
                         const float* __restrict__ scale_ws,
                         float* __restrict__ alpha_out, int E)
{
    int i = blockIdx.x * blockDim.x + threadIdx.x;
    if (i >= E) return;
    int sn = srcI[i], dn = dstI[i];
    float lg = a_src[sn] + a_dst[dn];
    lg = lg > 0.0f ? lg : NEG_GAT * lg;
    alpha_out[i] = __expf(lg) * scale_ws[dn];
}

// ---- self-loop alpha ----
__global__ void k_alphaS(const float* __restrict__ a_src, const float* __restrict__ a_dst,
                         const float* __restrict__ scale_ws,
                         float* __restrict__ alpha_self, int N)
{
    int n = blockIdx.x * blockDim.x + threadIdx.x;
    if (n >= N) return;
    float lg = a_src[n] + a_dst[n];
    lg = lg > 0.0f ? lg : NEG_GAT * lg;
    alpha_self[n] = __expf(lg) * scale_ws[n];
}

extern "C" void kernel_launch(void* const* d_in, const int* in_sizes, int n_in,
                              void* d_out, int out_size, void* d_ws, size_t ws_size,
                              hipStream_t stream)
{
    const int* x          = (const int*)d_in[0];
    const int* ei         = (const int*)d_in[1];
    const float* emb      = (const float*)d_in[2];
    const float* W        = (const float*)d_in[3];
    const float* att_src  = (const float*)d_in[4];
    const float* att_dst  = (const float*)d_in[5];
    const float* bias     = (const float*)d_in[6];

    const int N = in_sizes[0];
    const int E = in_sizes[1] / 2;
    const int* srcI = ei;       // edge_index[0]
    const int* dstI = ei + E;   // edge_index[1]
    const int NC = (N + CHUNK - 1) / CHUNK;
    const int NB = (N + (1 << BSH) - 1) >> BSH;
    const int EN = E + N;

    char* p = (char*)d_ws;
    size_t off = 0;
    auto take = [&](size_t bytes) {
        char* q = p + off;
        off += (bytes + 15) & ~size_t(15);
        return q;
    };
    int* partial      = (int*)take((size_t)NC * 4);
    int* rp           = (int*)take((size_t)N * 4);
    float* a_src_b    = (float*)take((size_t)N * 4);
    float* a_dst_b    = (float*)take((size_t)N * 4);
    float* scale_ws   = (float*)take((size_t)N * 4);
    int* perm         = (int*)take((size_t)EN * 4);
    int* bh           = (int*)take((size_t)(NBMAX + 1) * 4);
    int* bcur         = (int*)take((size_t)NBMAX * 4);
    unsigned* staging = (unsigned*)take((size_t)EN * 4);   // no aliasing (replay-safe, r13)
    bf16* hb          = (bf16*)take((size_t)N * D * 2);    // total ~28 MB (< proven 33.6)

    float* out       = (float*)d_out;
    float* alpha_out = out + (long long)N * D;

    const bool bucketed = (NB <= NBMAX) && (N < (1 << 23));
    const int node_grid = min(NODE_BLOCKS, (N + 3) / 4);

    k_node  <<<node_grid, 256, 0, stream>>>(x, emb, W, att_src, att_dst,
                                            hb, a_src_b, a_dst_b, N);
    if (bucketed) {
        k_bzero <<<(NBMAX + 256) / 256, 256, 0, stream>>>(bh, NBMAX + 1);
        k_bhist <<<512, 256, 0, stream>>>(dstI, bh, E, N);
        k_bscan <<<1, NBMAX, 0, stream>>>(bh, bcur, NB);
        k_part  <<<(EN + 256 * PART_K - 1) / (256 * PART_K), 256, 0, stream>>>(
                    srcI, dstI, bcur, staging, E, N);
        k_place3<<<NB, 256, 0, stream>>>(staging, bh, bcur, rp, perm, N);
    } else {
        k_init  <<<(N + 255) / 256, 256, 0, stream>>>(rp, N);
        k_count <<<(E + 255) / 256, 256, 0, stream>>>(dstI, rp, E);
        k_scan1 <<<NC, CHUNK, 0, stream>>>(rp, partial, N);
        k_scan2 <<<1, 512, 0, stream>>>(partial, NC);
        k_scan3 <<<NC, CHUNK, 0, stream>>>(rp, partial, N);
        k_place <<<(EN + 255) / 256, 256, 0, stream>>>(srcI, dstI, rp, perm, E, N);
    }
    k_agg   <<<(N + 3) / 4, 256, 0, stream>>>(rp, perm, a_src_b, a_dst_b,
                                              hb, bias, out, scale_ws, E, N);
    k_alphaE<<<(E + 255) / 256, 256, 0, stream>>>(srcI, dstI, a_src_b, a_dst_b,
                                                  scale_ws, alpha_out, E);
    k_alphaS<<<(N + 255) / 256, 256, 0, stream>>>(a_src_b, a_dst_b, scale_ws,
                                                  alpha_out + E, N);
}